// Round 7
// baseline (107.756 us; speedup 1.0000x reference)
//
#include <hip/hip_runtime.h>
#include <cstdint>

// m=8, n=4096, dx=2, dz=16, grid 64x64 -> M=4096. All I/O fp32.
// R6: ONE kernel, ONE block per (gtile, b) -> 512 blocks of 512 threads,
// all co-resident (2 blocks/CU at 64.3 KB LDS) -> makespan = heaviest block,
// no inter-block serialization, no ws partials, no combine kernel.
//  - Phase A: compact survivors (e0 = q0*d0^2 folded, x1) into LDS.
//  - Phase B: double-buffered staging of 128 z-rows/chunk (1 float4/thread)
//    + branch-free compute from LDS broadcast reads.
//  - 7-wave LDS reduction (aliased over dead zbuf/list/xs), direct store.
#define N_PTS   4096
#define M_GRID  4096
#define CHUNK   128                 // survivor rows per staged chunk
#define REDSTR  17
#define SKIP_E0 -20.0f              // exp(-20)=2e-9; skip error < 4e-5

// LDS layout (manual union), 65540 B total -> 2 blocks/CU:
//   [0     .. 16384)  zbuf: float4[2][CHUNK*4]
//   [16384 .. 32768)  list: int[N_PTS]
//   [32768 .. 65536)  xs:   float2[N_PTS]   (.x = e0, .y = x1)
//   [65536 .. 65540)  cnt
//   [0     .. 30464)  red:  float[7*64*REDSTR]  (reduction phase, aliases)
#define SMEM_BYTES 65540

__global__ __launch_bounds__(512, 4)
void setconv_kernel(const float2* __restrict__ x2,     // [8*4096]
                    const float4* __restrict__ z4,     // [8*4096*4]
                    const float*  __restrict__ lsp,    // [2]
                    const float2* __restrict__ grid2,  // [4096]
                    float2*       __restrict__ outx,   // x_grid [8*4096]
                    float*        __restrict__ outz)   // z_grid [8*4096*16]
{
    __shared__ __align__(16) char smem[SMEM_BYTES];
    float4* zbuf = reinterpret_cast<float4*>(smem);              // [2][512]
    int*    list = reinterpret_cast<int*>(smem + 16384);         // [N_PTS]
    float2* xs   = reinterpret_cast<float2*>(smem + 32768);      // [N_PTS]
    int*    cntp = reinterpret_cast<int*>(smem + 65536);
    float*  red  = reinterpret_cast<float*>(smem);               // aliases!

    const int tid   = threadIdx.x;
    const int lane  = tid & 63;
    const int w     = tid >> 6;             // wave 0..7
    const int gtile = blockIdx.x;           // 0..63 (grid row; g0 uniform)
    const int b     = blockIdx.y;           // 0..7

    // lengthscale = 1e-5 + softplus(param)
    float p0 = lsp[0], p1 = lsp[1];
    float sp0 = (p0 > 0.f) ? (p0 + log1pf(expf(-p0))) : log1pf(expf(p0));
    float sp1 = (p1 > 0.f) ? (p1 + log1pf(expf(-p1))) : log1pf(expf(p1));
    float ls0 = 1e-5f + sp0, ls1 = 1e-5f + sp1;
    const float q0 = -0.5f / (ls0 * ls0);   // wgt = exp(q0*d0^2 + q1*d1^2)
    const float q1 = -0.5f / (ls1 * ls1);

    const int    g  = gtile * 64 + lane;
    const float2 gv = grid2[g];
    const float  g0 = gv.x;                 // block-uniform (row coord)
    const float  g1 = gv.y;                 // per-lane (col coord)

    // fused x_grid write
    if (w == 0) outx[(size_t)b * M_GRID + g] = gv;

    if (tid == 0) *cntp = 0;
    __syncthreads();

    const float2* xb = x2 + b * N_PTS;
    const float4* zb = z4 + (size_t)b * N_PTS * 4;

    // ---- Phase A: compact survivors; store (e0 = q0*d0^2, x1) ----
    for (int t = tid; t < N_PTS; t += 512) {
        float2 xv = xb[t];
        float d0 = g0 - xv.x;
        float e0 = q0 * d0 * d0;
        bool keep = (e0 >= SKIP_E0);
        unsigned long long m = __ballot(keep);
        int base = 0;
        if (lane == 0 && m) base = atomicAdd(cntp, __popcll(m));
        base = __shfl(base, 0);
        if (keep) {
            int off = __popcll(m & ((1ull << lane) - 1ull));
            list[base + off] = t;
            xs[base + off]   = make_float2(e0, xv.y);
        }
    }
    __syncthreads();
    const int C    = *cntp;
    const int Cpad = (C + CHUNK - 1) & ~(CHUNK - 1);
    for (int t = C + tid; t < Cpad; t += 512) {   // sentinel pad -> wgt = 0
        list[t] = 0;
        xs[t]   = make_float2(-1e30f, 0.f);
    }
    __syncthreads();

    float acc[16];
#pragma unroll
    for (int d = 0; d < 16; ++d) acc[d] = 0.f;

    const int nchunk = Cpad / CHUNK;

    // stage chunk ci: thread t -> survivor row ci*128+(t>>2), qword t&3
    auto stage = [&](int ci, int bufi) {
        int r = ci * CHUNK + (tid >> 2);
        int n = list[r];
        zbuf[bufi * (CHUNK * 4) + (tid >> 2) * 4 + (tid & 3)] =
            zb[(size_t)n * 4 + (tid & 3)];
    };

    if (nchunk > 0) stage(0, 0);
    __syncthreads();

    for (int ci = 0; ci < nchunk; ++ci) {
        const int cur = ci & 1;
        if (ci + 1 < nchunk) stage(ci + 1, cur ^ 1);

        const int base = ci * CHUNK + w * (CHUNK / 8);
        const float4* zrow = zbuf + cur * (CHUNK * 4) + w * (CHUNK / 8) * 4;
#pragma unroll 4
        for (int i = 0; i < CHUNK / 8; ++i) {       // 16 survivors per wave
            float2 xv = xs[base + i];               // broadcast LDS read
            float u   = g1 - xv.y;
            float wgt = __expf(fmaf(q1 * u, u, xv.x));
            const float4* zr = zrow + i * 4;
            float4 a0 = zr[0], a1 = zr[1], a2 = zr[2], a3 = zr[3];
            acc[0]  = fmaf(wgt, a0.x, acc[0]);  acc[1]  = fmaf(wgt, a0.y, acc[1]);
            acc[2]  = fmaf(wgt, a0.z, acc[2]);  acc[3]  = fmaf(wgt, a0.w, acc[3]);
            acc[4]  = fmaf(wgt, a1.x, acc[4]);  acc[5]  = fmaf(wgt, a1.y, acc[5]);
            acc[6]  = fmaf(wgt, a1.z, acc[6]);  acc[7]  = fmaf(wgt, a1.w, acc[7]);
            acc[8]  = fmaf(wgt, a2.x, acc[8]);  acc[9]  = fmaf(wgt, a2.y, acc[9]);
            acc[10] = fmaf(wgt, a2.z, acc[10]); acc[11] = fmaf(wgt, a2.w, acc[11]);
            acc[12] = fmaf(wgt, a3.x, acc[12]); acc[13] = fmaf(wgt, a3.y, acc[13]);
            acc[14] = fmaf(wgt, a3.z, acc[14]); acc[15] = fmaf(wgt, a3.w, acc[15]);
        }
        __syncthreads();
    }

    // ---- cross-wave reduction (red ALIASES zbuf/list/xs — all dead) ----
    if (w > 0) {
        float* dst = red + ((w - 1) * 64 + lane) * REDSTR;
#pragma unroll
        for (int d = 0; d < 16; ++d) dst[d] = acc[d];
    }
    __syncthreads();
    if (w == 0) {
#pragma unroll
        for (int j = 0; j < 7; ++j) {
            const float* src = red + (j * 64 + lane) * REDSTR;
#pragma unroll
            for (int d = 0; d < 16; ++d) acc[d] += src[d];
        }
        float4* op = reinterpret_cast<float4*>(outz) + ((size_t)(b * M_GRID + g) * 4);
        op[0] = make_float4(acc[0],  acc[1],  acc[2],  acc[3]);
        op[1] = make_float4(acc[4],  acc[5],  acc[6],  acc[7]);
        op[2] = make_float4(acc[8],  acc[9],  acc[10], acc[11]);
        op[3] = make_float4(acc[12], acc[13], acc[14], acc[15]);
    }
}

extern "C" void kernel_launch(void* const* d_in, const int* in_sizes, int n_in,
                              void* d_out, int out_size, void* d_ws, size_t ws_size,
                              hipStream_t stream) {
    // inputs (all fp32): x [8,4096,2], z [8,4096,16], lengthscale_param [2],
    // grid [64,64,2]. output: x_grid (65536 f32) ++ z_grid (524288 f32).
    const float2* x2    = (const float2*)d_in[0];
    const float4* z4    = (const float4*)d_in[1];
    const float*  lsp   = (const float*)d_in[2];
    const float2* grid2 = (const float2*)d_in[3];
    float* out = (float*)d_out;

    hipLaunchKernelGGL(setconv_kernel, dim3(64, 8), dim3(512), 0, stream,
                       x2, z4, lsp, grid2, (float2*)out, out + 65536);
}

// Round 8
// 88.614 us; speedup vs baseline: 1.2160x; 1.2160x over previous
//
#include <hip/hip_runtime.h>
#include <hip/hip_bf16.h>
#include <cstdint>

// m=8, n=4096, dx=2, dz=16, grid 64x64 -> M=4096. All I/O fp32.
// R7: per block (gtile,b), z_grid[64 cols][16 dz] = W[64 x C] * Z[C x 16]
// computed with mfma_f32_16x16x32_bf16:
//  - Phase A: compact survivors (e0 = q0*d0^2, x1) into LDS (block-uniform
//    predicate; g0 = axis0[gtile] shared by whole block).
//  - Phase B: per 64-survivor group, stage Z rows bf16 PRE-SWIZZLED into
//    B-fragment layout (lane = B[k=(lane>>4)*8+j][n=lane&15], one
//    ds_read_b128/wave/slab); each wave computes its A-frag (8 weights/lane,
//    exp in fp32, pack bf16) and issues ONE MFMA. Double-buffered staging.
//  - Waves (w, w+4) hold same M-tile over disjoint slabs -> 4 KB LDS reduce.
#define N_PTS   4096
#define M_GRID  4096
#define SKIP_E0 -20.0f              // exp(-20)=2e-9; skip error < 4e-5

typedef __attribute__((ext_vector_type(8))) short  short8;   // 8 bf16
typedef __attribute__((ext_vector_type(4))) float  floatx4;

// LDS layout:
//   [0     .. 16384)  list: int[4096]
//   [16384 .. 49152)  xs:   float2[4096]   (.x = e0, .y = x1)
//   [49152 .. 57344)  zfrag: 2 bufs x (2 slabs x 64 lanes x 8 bf16) = 8 KB
//   [49152 .. 53248)  red: floatx4[4][64]  (reduction phase, aliases zfrag)
//   [57344 .. 57348)  cnt
#define OFF_LIST 0
#define OFF_XS   16384
#define OFF_ZF   49152
#define OFF_RED  49152
#define OFF_CNT  57344
#define SMEM_BYTES 57348

__global__ __launch_bounds__(512, 4)
void setconv_kernel(const float2* __restrict__ x2,     // [8*4096]
                    const float4* __restrict__ z4,     // [8*4096*4]
                    const float*  __restrict__ lsp,    // [2]
                    const float2* __restrict__ grid2,  // [4096]
                    float2*       __restrict__ outx,   // x_grid [8*4096]
                    float*        __restrict__ outz)   // z_grid [8*4096*16]
{
    __shared__ __align__(16) char smem[SMEM_BYTES];
    int*            list = reinterpret_cast<int*>(smem + OFF_LIST);
    float2*         xs   = reinterpret_cast<float2*>(smem + OFF_XS);
    __hip_bfloat16* zf   = reinterpret_cast<__hip_bfloat16*>(smem + OFF_ZF);
    floatx4*        redv = reinterpret_cast<floatx4*>(smem + OFF_RED);
    int*            cntp = reinterpret_cast<int*>(smem + OFF_CNT);

    const int tid  = threadIdx.x;
    const int lane = tid & 63;
    const int w    = tid >> 6;          // wave 0..7
    const int mt   = w & 3;             // M-tile: grid cols mt*16..mt*16+15
    const int ks   = w >> 2;            // slab (0/1) within each 64-surv group
    const int gtile = blockIdx.x;       // 0..63 (grid row)
    const int b     = blockIdx.y;       // 0..7

    // lengthscale = 1e-5 + softplus(param)
    float p0 = lsp[0], p1 = lsp[1];
    float sp0 = (p0 > 0.f) ? (p0 + log1pf(expf(-p0))) : log1pf(expf(p0));
    float sp1 = (p1 > 0.f) ? (p1 + log1pf(expf(-p1))) : log1pf(expf(p1));
    float ls0 = 1e-5f + sp0, ls1 = 1e-5f + sp1;
    const float q0 = -0.5f / (ls0 * ls0);   // wgt = exp(q0*d0^2 + q1*d1^2)
    const float q1 = -0.5f / (ls1 * ls1);

    const float2 gv = grid2[gtile * 64 + lane];
    const float  g0 = gv.x;                 // block-uniform row coord
    // fused x_grid write
    if (w == 0) outx[(size_t)b * M_GRID + gtile * 64 + lane] = gv;
    // col coord for this lane's A-fragment row (m = lane&15 within M-tile)
    const float g1m = grid2[gtile * 64 + mt * 16 + (lane & 15)].y;

    if (tid == 0) *cntp = 0;
    __syncthreads();

    const float2* xb  = x2 + b * N_PTS;
    const float2* zb2 = reinterpret_cast<const float2*>(z4 + (size_t)b * N_PTS * 4);

    // ---- Phase A: compact survivors; store (e0, x1) ----
    for (int t = tid; t < N_PTS; t += 512) {
        float2 xv = xb[t];
        float d0 = g0 - xv.x;
        float e0 = q0 * d0 * d0;
        bool keep = (e0 >= SKIP_E0);
        unsigned long long m = __ballot(keep);
        int base = 0;
        if (lane == 0 && m) base = atomicAdd(cntp, __popcll(m));
        base = __shfl(base, 0);
        if (keep) {
            int off = __popcll(m & ((1ull << lane) - 1ull));
            list[base + off] = t;
            xs[base + off]   = make_float2(e0, xv.y);
        }
    }
    __syncthreads();
    const int C    = *cntp;
    const int Cpad = (C + 63) & ~63;
    for (int t = C + tid; t < Cpad; t += 512) {   // sentinel: wgt=exp(-1e30)=0
        list[t] = 0;
        xs[t]   = make_float2(-1e30f, 0.f);
    }
    __syncthreads();

    const int ngroup = Cpad >> 6;       // 64 survivors (2 K-slabs) per group

    // stage group gi: 512 threads, thread -> (survivor row = tid>>3, float2
    // pair p = tid&7); write bf16 into B-frag order:
    //   element (k, d) at zf[buf*2048 + sg*1024 + L*8 + (k&7)],
    //   L = ((k>>3)<<4) | d   (lane that owns it), k = row&31, sg = row>>5.
    auto stage = [&](int gi, int bufi) {
        int row = tid >> 3;
        int p   = tid & 7;
        int n   = list[gi * 64 + row];
        float2 zz = zb2[(size_t)n * 8 + p];
        int sg = row >> 5, k = row & 31;
        int base = bufi * 2048 + sg * 1024 + (k & 7);
        int L0 = ((k >> 3) << 4) | (2 * p);
        zf[base + L0 * 8]       = __float2bfloat16(zz.x);
        zf[base + (L0 + 1) * 8] = __float2bfloat16(zz.y);
    };

    floatx4 acc = {0.f, 0.f, 0.f, 0.f};

    if (ngroup > 0) stage(0, 0);
    __syncthreads();

    for (int gi = 0; gi < ngroup; ++gi) {
        const int cur = gi & 1;
        if (gi + 1 < ngroup) stage(gi + 1, cur ^ 1);

        // B-frag: one 16-B LDS read (lane-contiguous, pre-swizzled)
        short8 bfrag = *reinterpret_cast<const short8*>(
            smem + OFF_ZF + cur * 4096 + ks * 2048 + lane * 16);

        // A-frag: 8 weights for survivors k0..k0+7, this lane's col g1m
        const int k0 = gi * 64 + ks * 32 + (lane >> 4) * 8;
        union { uint32_t u[4]; short8 s; } af;
#pragma unroll
        for (int jp = 0; jp < 4; ++jp) {
            float2 s0 = xs[k0 + 2 * jp];
            float2 s1 = xs[k0 + 2 * jp + 1];
            float u0 = g1m - s0.y;
            float u1 = g1m - s1.y;
            float w0 = __expf(fmaf(q1 * u0, u0, s0.x));
            float w1 = __expf(fmaf(q1 * u1, u1, s1.x));
            union { __hip_bfloat162 h; uint32_t u; } cc;
            cc.h = __float22bfloat162_rn(make_float2(w0, w1));
            af.u[jp] = cc.u;
        }

        acc = __builtin_amdgcn_mfma_f32_16x16x32_bf16(af.s, bfrag, acc, 0, 0, 0);
        __syncthreads();
    }

    // ---- reduce wave pairs (w, w+4): same M-tile, disjoint slabs ----
    if (w >= 4) redv[(w - 4) * 64 + lane] = acc;   // aliases dead zfrag
    __syncthreads();
    if (w < 4) {
        floatx4 o = redv[mt * 64 + lane];
        acc += o;
        // D layout (m89): D[m = (lane>>4)*4 + r][n = lane&15]
        const int n = lane & 15;
        size_t base = ((size_t)b * M_GRID + gtile * 64 + mt * 16 +
                       (lane >> 4) * 4) * 16 + n;
#pragma unroll
        for (int r = 0; r < 4; ++r)
            outz[base + (size_t)r * 16] = acc[r];
    }
}

extern "C" void kernel_launch(void* const* d_in, const int* in_sizes, int n_in,
                              void* d_out, int out_size, void* d_ws, size_t ws_size,
                              hipStream_t stream) {
    // inputs (all fp32): x [8,4096,2], z [8,4096,16], lengthscale_param [2],
    // grid [64,64,2]. output: x_grid (65536 f32) ++ z_grid (524288 f32).
    const float2* x2    = (const float2*)d_in[0];
    const float4* z4    = (const float4*)d_in[1];
    const float*  lsp   = (const float*)d_in[2];
    const float2* grid2 = (const float2*)d_in[3];
    float* out = (float*)d_out;

    hipLaunchKernelGGL(setconv_kernel, dim3(64, 8), dim3(512), 0, stream,
                       x2, z4, lsp, grid2, (float2*)out, out + 65536);
}